// Round 10
// baseline (105.803 us; speedup 1.0000x reference)
//
#include <hip/hip_runtime.h>
#include <math.h>

// Problem shape (fixed by setup_inputs): logits [8,12,256,256] fp32, targets [8,256,256] i32.
constexpr int B_  = 8;
constexpr int C_  = 12;
constexpr int H_  = 256;
constexpr int W_  = 256;
constexpr int HW_ = H_ * W_;
constexpr int NBC_ = B_ * C_;           // 96
constexpr int VB_  = NBC_ * 8;          // vert tiles (768): 32 columns per tile
constexpr int SMB_ = B_ * (HW_ / 1024); // probs blocks (512): 512 thr x 2 px
constexpr int PADL_ = 128;              // LDS pad: covers r<=128 affine reads
constexpr int LROW_ = PADL_ + W_ + PADL_;  // 512 floats per LDS row

// Packed vertical-EDT value: bit15 = is_fg (t==c); bits[14:0] = vertical
// distance d to nearest zero of the pixel's own nonzero transform
// (0x7FFF = no zero in column -> reference g = 1e6 - h). The OTHER
// transform's g is always 0 at this pixel, so one u16 encodes both.

// ---------------------------------------------------------------------------
// K1 (merged, 512 thr): blocks [0,768) = vertical EDT (32 cols x 16 segments
// x 16 rows); blocks [768,768+512) = softmax PROBS for all 12 classes
// (2 px/thread). pr = __expf(l-mx)*(1/s): identical ops/order -> bit-identical.
// Block 0 zeroes out[0] (consumed by k_bcred two dispatches later).
// ---------------------------------------------------------------------------
__global__ void __launch_bounds__(512) k_vs(
                     const int* __restrict__ t,
                     const float* __restrict__ logits,
                     unsigned short* __restrict__ gpk,
                     int* __restrict__ hasfg_p,
                     float* __restrict__ probs,
                     float* __restrict__ out) {
    int tid = threadIdx.x;
    if (blockIdx.x >= VB_) {
        // ---- probs branch: 512 thr x 2 px, all 12 classes ----
        int pb = blockIdx.x - VB_;             // [0, 512)
        int b = pb >> 6;
        int p = ((pb & 63) << 10) + tid * 2;
        const float* lb = logits + (size_t)b * C_ * HW_ + p;
        float2 l[C_];
        float mxx = -3.4e38f, mxy = -3.4e38f;
        #pragma unroll
        for (int c = 0; c < C_; ++c) {
            l[c] = *(const float2*)(lb + (size_t)c * HW_);
            mxx = fmaxf(mxx, l[c].x);
            mxy = fmaxf(mxy, l[c].y);
        }
        float sx = 0.f, sy = 0.f;
        #pragma unroll
        for (int c = 0; c < C_; ++c) {
            l[c].x = __expf(l[c].x - mxx);     // in-place: e[c]
            l[c].y = __expf(l[c].y - mxy);
            sx += l[c].x;
            sy += l[c].y;
        }
        float ix = 1.0f / sx, iy = 1.0f / sy;
        float* pbp = probs + (size_t)b * C_ * HW_ + p;
        #pragma unroll
        for (int c = 0; c < C_; ++c) {
            *(float2*)(pbp + (size_t)c * HW_) = make_float2(l[c].x * ix, l[c].y * iy);
        }
        return;
    }

    // ---- vertical EDT branch (R8 geometry, proven) ----
    if (blockIdx.x == 0 && tid == 0) out[0] = 0.0f;   // replaces memset dispatch
    constexpr int SEG = 16, SH = 16;
    int s  = tid >> 5;          // segment 0..15
    int wl = tid & 31;          // column within tile
    int blk = blockIdx.x;       // 96*8
    int bc = blk >> 3;
    int w0 = (blk & 7) * 32;
    int b = bc / C_, c = bc - b * C_;
    int w = w0 + wl;
    const int* base = t + b * HW_ + w;
    int h0 = s * SH;

    unsigned tp[SH / 4];        // 4 regs: u8-packed targets for this segment
    int lastEq = -1, lastNeq = -1, firstEq = 256, firstNeq = 256;
    #pragma unroll
    for (int i = 0; i < SH; ++i) {
        int tv = base[(h0 + i) * W_];
        if ((i & 3) == 0) tp[i >> 2] = 0;
        tp[i >> 2] |= (unsigned)tv << ((i & 3) * 8);
        int h = h0 + i;
        if (tv == c) { lastEq = h;  if (firstEq  == 256) firstEq  = h; }
        else         { lastNeq = h; if (firstNeq == 256) firstNeq = h; }
    }
    __shared__ int sLE[SEG][32], sLN[SEG][32], sFE[SEG][32], sFN[SEG][32];
    sLE[s][wl] = lastEq; sLN[s][wl] = lastNeq;
    sFE[s][wl] = firstEq; sFN[s][wl] = firstNeq;
    __syncthreads();

    int carLE = -1, carLN = -1;
    for (int q = 0; q < s; ++q) {
        carLE = max(carLE, sLE[q][wl]);
        carLN = max(carLN, sLN[q][wl]);
    }
    int carFE = 256, carFN = 256;
    for (int q = s + 1; q < SEG; ++q) {
        carFE = min(carFE, sFE[q][wl]);
        carFN = min(carFN, sFN[q][wl]);
    }

    // tile has-fg: wave 0 lanes 0..31 each own a column
    bool pred = false;
    if (tid < 32) {
        int m = -1;
        #pragma unroll
        for (int q = 0; q < SEG; ++q) m = max(m, sLE[q][tid]);
        pred = (m >= 0);
    }
    bool anyfg = __any(pred);
    if (tid == 0) hasfg_p[blk] = anyfg ? 1 : 0;

    // forward pass: u8-encode dl-1 (255 = no zero at-or-above)
    unsigned ap[SH / 4];
    {
        int le = carLE, ln = carLN;
        #pragma unroll
        for (int i = 0; i < SH; ++i) {
            int h = h0 + i;
            int tv = (tp[i >> 2] >> ((i & 3) * 8)) & 0xFF;
            int lz;
            if (tv == c) { le = h; lz = ln; } else { ln = h; lz = le; }
            unsigned a = (lz < 0) ? 255u : (unsigned)(h - lz - 1);
            if ((i & 3) == 0) ap[i >> 2] = 0;
            ap[i >> 2] |= a << ((i & 3) * 8);
        }
    }
    // backward pass: d = min(dl, dn), u16 store
    {
        int fe = carFE, fn = carFN;
        unsigned short* gk = gpk + (size_t)bc * HW_ + w;
        #pragma unroll
        for (int i = SH - 1; i >= 0; --i) {
            int h = h0 + i;
            int tv = (tp[i >> 2] >> ((i & 3) * 8)) & 0xFF;
            int nz; bool fg;
            if (tv == c) { fe = h; fg = true;  nz = fn; }
            else         { fn = h; fg = false; nz = fe; }
            unsigned au = (ap[i >> 2] >> ((i & 3) * 8)) & 0xFF;
            int dl  = (au == 255u) ? 0x7FFF : (int)au + 1;
            int dnx = (nz > 255) ? 0x7FFF : (nz - h);
            int d = min(dl, dnx);
            gk[h * W_] = (unsigned short)(d | (fg ? 0x8000 : 0));
        }
    }
}

// ---------------------------------------------------------------------------
// K2 (fused): per-row horizontal EDT + raw dice sums. One wave per (bc,h)
// row; 4 rows (same bc) per block. Own-class prob loaded from probs.
// SCAN CHANGE vs R9: vote every 4 radii (chunked). Each chunk issues 4
// radius-updates unconditionally (32 independent ds_reads batched -> 4x MLP
// per serialized segment), then one __any vote. Bit-identical: once
// r^2 >= max(bn), fminf(bn, r^2+v) is a no-op (v>=0), so the <=3 extra
// updates past the original break radius change nothing.
// r>128 rare clamped tail keeps per-r votes.
// ---------------------------------------------------------------------------
__global__ void __launch_bounds__(256) k_edt(
                      const unsigned short* __restrict__ gpk,
                      const float* __restrict__ probs,
                      const int* __restrict__ hasfg_p,
                      float* __restrict__ part) {
    __shared__ float sp[4][LROW_];
    __shared__ float sn[4][LROW_];
    int wave = threadIdx.x >> 6;
    int lane = threadIdx.x & 63;
    int row = blockIdx.x * 4 + wave;       // bc*256 + h; all 4 rows same bc
    int bc = row >> 8;
    int h = row & (H_ - 1);

    int hfl = 0;
    if (lane < 8) hfl = hasfg_p[bc * 8 + lane];
    bool hf = __any(hfl != 0);             // uniform across block (same bc)

    // hoist the prob loads: latency hides under the EDT scans
    const float* prow = probs + (size_t)bc * HW_ + h * W_;
    float pv[4];
    #pragma unroll
    for (int i = 0; i < 4; ++i) pv[i] = prow[lane + 64 * i];

    float dv[4];
    if (hf) {
        const ushort4 v4 = ((const ushort4*)(gpk + (size_t)row * W_))[lane];

        // pad init: left pad = float4 slots [0,32), right pad = slots [96,128)
        float4 inf4 = make_float4(3.0e38f, 3.0e38f, 3.0e38f, 3.0e38f);
        int slot = (lane < 32) ? lane : (lane + 64);
        ((float4*)&sp[wave][0])[slot] = inf4;
        ((float4*)&sn[wave][0])[slot] = inf4;

        float s1 = (float)(1000000 - h);
        float sent2 = s1 * s1;             // == fl((1e6 - h)^2), reference-exact
        float4 fpv, fnv;
        {
            const unsigned short* vs = (const unsigned short*)&v4;
            float* fp = (float*)&fpv;
            float* fn = (float*)&fnv;
            #pragma unroll
            for (int q = 0; q < 4; ++q) {
                unsigned v = vs[q];
                unsigned d = v & 0x7FFFu;
                float g2 = (d == 0x7FFFu) ? sent2 : (float)(d * d);
                bool fg = (v & 0x8000u) != 0;
                fp[q] = fg ? g2 : 0.0f;
                fn[q] = fg ? 0.0f : g2;
            }
        }
        ((float4*)&sp[wave][PADL_])[lane] = fpv;   // data at [128, 384)
        ((float4*)&sn[wave][PADL_])[lane] = fnv;
        // wave-private LDS rows: wave-local wait suffices (no barrier)
        asm volatile("s_waitcnt lgkmcnt(0)" ::: "memory");

        float bp[4], bn[4];
        #pragma unroll
        for (int i = 0; i < 4; ++i) {
            int j = PADL_ + lane + 64 * i;
            bp[i] = sp[wave][j];
            bn[i] = sn[wave][j];
        }
        // ---- neg transform scan: chunk-4 voting ----
        {
            bool doneN = false;
            int rb = 1;
            for (; rb <= PADL_ - 3; rb += 4) {     // affine fast path
                float m = fmaxf(fmaxf(bn[0], bn[1]), fmaxf(bn[2], bn[3]));
                float frb = (float)rb;
                if (!__any(frb * frb < m)) { doneN = true; break; }
                #pragma unroll
                for (int u = 0; u < 4; ++u) {
                    int r = rb + u;
                    float fr = (float)r;
                    #pragma unroll
                    for (int i = 0; i < 4; ++i) {
                        int j = PADL_ + lane + 64 * i;
                        float v = fminf(sn[wave][j - r], sn[wave][j + r]);
                        bn[i] = fminf(bn[i], fmaf(fr, fr, v));
                    }
                }
            }
            if (!doneN) {
                for (int r = PADL_ + 1; r < W_; ++r) {  // rare tail: clamped
                    float fr = (float)r;
                    float r2 = fr * fr;
                    float m = fmaxf(fmaxf(bn[0], bn[1]), fmaxf(bn[2], bn[3]));
                    if (!__any(r2 < m)) break;
                    #pragma unroll
                    for (int i = 0; i < 4; ++i) {
                        int j = PADL_ + lane + 64 * i;
                        int jm = max(j - r, 0);
                        int jp = min(j + r, LROW_ - 1);
                        float v = fminf(sn[wave][jm], sn[wave][jp]);
                        bn[i] = fminf(bn[i], fmaf(fr, fr, v));
                    }
                }
            }
        }
        // ---- pos transform scan: chunk-4 voting ----
        {
            bool doneP = false;
            int rb = 1;
            for (; rb <= PADL_ - 3; rb += 4) {     // affine fast path
                float m = fmaxf(fmaxf(bp[0], bp[1]), fmaxf(bp[2], bp[3]));
                float frb = (float)rb;
                if (!__any(frb * frb < m)) { doneP = true; break; }
                #pragma unroll
                for (int u = 0; u < 4; ++u) {
                    int r = rb + u;
                    float fr = (float)r;
                    #pragma unroll
                    for (int i = 0; i < 4; ++i) {
                        int j = PADL_ + lane + 64 * i;
                        float v = fminf(sp[wave][j - r], sp[wave][j + r]);
                        bp[i] = fminf(bp[i], fmaf(fr, fr, v));
                    }
                }
            }
            if (!doneP) {
                for (int r = PADL_ + 1; r < W_; ++r) {  // rare tail: clamped
                    float fr = (float)r;
                    float r2 = fr * fr;
                    float m = fmaxf(fmaxf(bp[0], bp[1]), fmaxf(bp[2], bp[3]));
                    if (!__any(r2 < m)) break;
                    #pragma unroll
                    for (int i = 0; i < 4; ++i) {
                        int j = PADL_ + lane + 64 * i;
                        int jm = max(j - r, 0);
                        int jp = min(j + r, LROW_ - 1);
                        float v = fminf(sp[wave][jm], sp[wave][jp]);
                        bp[i] = fminf(bp[i], fmaf(fr, fr, v));
                    }
                }
            }
        }
        #pragma unroll
        for (int i = 0; i < 4; ++i) dv[i] = sqrtf(bn[i]) - sqrtf(bp[i]);
    } else {
        #pragma unroll
        for (int i = 0; i < 4; ++i) dv[i] = 0.0f;
    }

    // raw sums over 256 pixels (pr from probs; order identical to before)
    float s_pd = 0.f, s_p = 0.f, s_pp = 0.f, s_d = 0.f, s_dd = 0.f;
    float mn = 3.4e38f, mx = -3.4e38f;
    #pragma unroll
    for (int i = 0; i < 4; ++i) {
        float pr = pv[i];
        float d = dv[i];
        s_pd = fmaf(pr, d, s_pd);
        s_p += pr;
        s_pp = fmaf(pr, pr, s_pp);
        s_d += d;
        s_dd = fmaf(d, d, s_dd);
        mn = fminf(mn, d);
        mx = fmaxf(mx, d);
    }
    #pragma unroll
    for (int off = 32; off; off >>= 1) {
        s_pd += __shfl_down(s_pd, off);
        s_p  += __shfl_down(s_p, off);
        s_pp += __shfl_down(s_pp, off);
        s_d  += __shfl_down(s_d, off);
        s_dd += __shfl_down(s_dd, off);
        mn = fminf(mn, __shfl_down(mn, off));
        mx = fmaxf(mx, __shfl_down(mx, off));
    }
    if (lane == 0) {
        float4* p4 = (float4*)(part + (size_t)row * 8);   // 32B-aligned
        p4[0] = make_float4(s_pd, s_p, s_pp, s_d);
        p4[1] = make_float4(s_dd, mn, mx, 0.0f);
    }
}

// ---------------------------------------------------------------------------
// K3: per-(b,c) reduce of 256 row partials -> dice -> atomicAdd loss term.
// out[0] zeroed by k_vs block 0. inter = sc*(S_pd - mn*S_p);
// d2 = sc^2*(S_dd - 2 mn S_d + mn^2 N). 96 atomics total.
// ---------------------------------------------------------------------------
__global__ void __launch_bounds__(256) k_bcred(
                       const float* __restrict__ part, float* __restrict__ out) {
    int bc = blockIdx.x;
    int tid = threadIdx.x;                 // 256
    const float4* p4 = (const float4*)(part + ((size_t)bc * 256 + tid) * 8);
    float4 a = p4[0], bq = p4[1];
    float s_pd = a.x, s_p = a.y, s_pp = a.z;
    float s_d = a.w, s_dd = bq.x, mn = bq.y, mx = bq.z;
    #pragma unroll
    for (int off = 32; off; off >>= 1) {
        s_pd += __shfl_down(s_pd, off);
        s_p  += __shfl_down(s_p, off);
        s_pp += __shfl_down(s_pp, off);
        s_d  += __shfl_down(s_d, off);
        s_dd += __shfl_down(s_dd, off);
        mn = fminf(mn, __shfl_down(mn, off));
        mx = fmaxf(mx, __shfl_down(mx, off));
    }
    __shared__ float red[4][7];
    int wave = tid >> 6, lane = tid & 63;
    if (lane == 0) {
        red[wave][0] = s_pd; red[wave][1] = s_p; red[wave][2] = s_pp;
        red[wave][3] = s_d;  red[wave][4] = s_dd; red[wave][5] = mn; red[wave][6] = mx;
    }
    __syncthreads();
    if (tid == 0) {
        s_pd = red[0][0]; s_p = red[0][1]; s_pp = red[0][2];
        s_d = red[0][3]; s_dd = red[0][4]; mn = red[0][5]; mx = red[0][6];
        for (int w = 1; w < 4; ++w) {
            s_pd += red[w][0]; s_p += red[w][1]; s_pp += red[w][2];
            s_d += red[w][3]; s_dd += red[w][4];
            mn = fminf(mn, red[w][5]); mx = fmaxf(mx, red[w][6]);
        }
        float sc = 1.0f / (mx - mn + 1e-8f);
        float inter = sc * (s_pd - mn * s_p);
        float d2 = sc * sc * (s_dd - 2.0f * mn * s_d + mn * mn * (float)HW_);
        float dice = 2.0f * inter / (s_pp + d2 + 1e-6f);
        atomicAdd(out, (1.0f - dice) * (1.0f / (float)NBC_));
    }
}

// ---------------------------------------------------------------------------
extern "C" void kernel_launch(void* const* d_in, const int* in_sizes, int n_in,
                              void* d_out, int out_size, void* d_ws, size_t ws_size,
                              hipStream_t stream) {
    const float* logits  = (const float*)d_in[0];
    const int*   targets = (const int*)d_in[1];
    float* out = (float*)d_out;

    // ws layout: gpk u16[96*65536] | hasfg_p i32[768] | part f32[24576*8] |
    //            probs f32[8*12*65536]
    unsigned short* gpk = (unsigned short*)d_ws;
    int* hasfg_p = (int*)(gpk + (size_t)NBC_ * HW_);
    float* part = (float*)(hasfg_p + NBC_ * 8);
    float* probs = part + (size_t)NBC_ * H_ * 8;

    k_vs<<<VB_ + SMB_, 512, 0, stream>>>(targets, logits, gpk,
                                         hasfg_p, probs, out);
    k_edt<<<NBC_ * H_ / 4, 256, 0, stream>>>(gpk, probs, hasfg_p, part);
    k_bcred<<<NBC_, 256, 0, stream>>>(part, out);
}

// Round 11
// 103.768 us; speedup vs baseline: 1.0196x; 1.0196x over previous
//
#include <hip/hip_runtime.h>
#include <math.h>

// Problem shape (fixed by setup_inputs): logits [8,12,256,256] fp32, targets [8,256,256] i32.
constexpr int B_  = 8;
constexpr int C_  = 12;
constexpr int H_  = 256;
constexpr int W_  = 256;
constexpr int HW_ = H_ * W_;
constexpr int NBC_ = B_ * C_;           // 96
constexpr int VB_  = NBC_ * 8;          // vert tiles (768): 32 columns per tile
constexpr int SMB_ = B_ * (HW_ / 1024); // probs blocks (512): 512 thr x 2 px
constexpr int PADL_ = 128;              // LDS pad: covers r<=128 affine reads
constexpr int LROW_ = PADL_ + W_ + PADL_;  // 512 floats per LDS row

// Packed vertical-EDT value: bit15 = is_fg (t==c); bits[14:0] = vertical
// distance d to nearest zero of the pixel's own nonzero transform
// (0x7FFF = no zero in column -> reference g = 1e6 - h). The OTHER
// transform's g is always 0 at this pixel, so one u16 encodes both.

// ---------------------------------------------------------------------------
// K1 (merged, 512 thr): blocks [0,768) = vertical EDT (32 cols x 16 segments
// x 16 rows); blocks [768,768+512) = softmax PROBS for all 12 classes
// (2 px/thread). pr = __expf(l-mx)*(1/s): identical ops/order -> bit-identical.
// Block 0 zeroes out[0] (consumed by k_bcred two dispatches later).
// NOTE (session model): this dispatch largely overlaps the harness's 256 MiB
// workspace re-poison fill (~44us, HBM-saturating), so its solo time is
// mostly hidden; k_edt below is the controllable tail.
// ---------------------------------------------------------------------------
__global__ void __launch_bounds__(512) k_vs(
                     const int* __restrict__ t,
                     const float* __restrict__ logits,
                     unsigned short* __restrict__ gpk,
                     int* __restrict__ hasfg_p,
                     float* __restrict__ probs,
                     float* __restrict__ out) {
    int tid = threadIdx.x;
    if (blockIdx.x >= VB_) {
        // ---- probs branch: 512 thr x 2 px, all 12 classes ----
        int pb = blockIdx.x - VB_;             // [0, 512)
        int b = pb >> 6;
        int p = ((pb & 63) << 10) + tid * 2;
        const float* lb = logits + (size_t)b * C_ * HW_ + p;
        float2 l[C_];
        float mxx = -3.4e38f, mxy = -3.4e38f;
        #pragma unroll
        for (int c = 0; c < C_; ++c) {
            l[c] = *(const float2*)(lb + (size_t)c * HW_);
            mxx = fmaxf(mxx, l[c].x);
            mxy = fmaxf(mxy, l[c].y);
        }
        float sx = 0.f, sy = 0.f;
        #pragma unroll
        for (int c = 0; c < C_; ++c) {
            l[c].x = __expf(l[c].x - mxx);     // in-place: e[c]
            l[c].y = __expf(l[c].y - mxy);
            sx += l[c].x;
            sy += l[c].y;
        }
        float ix = 1.0f / sx, iy = 1.0f / sy;
        float* pbp = probs + (size_t)b * C_ * HW_ + p;
        #pragma unroll
        for (int c = 0; c < C_; ++c) {
            *(float2*)(pbp + (size_t)c * HW_) = make_float2(l[c].x * ix, l[c].y * iy);
        }
        return;
    }

    // ---- vertical EDT branch (R8 geometry, proven) ----
    if (blockIdx.x == 0 && tid == 0) out[0] = 0.0f;   // replaces memset dispatch
    constexpr int SEG = 16, SH = 16;
    int s  = tid >> 5;          // segment 0..15
    int wl = tid & 31;          // column within tile
    int blk = blockIdx.x;       // 96*8
    int bc = blk >> 3;
    int w0 = (blk & 7) * 32;
    int b = bc / C_, c = bc - b * C_;
    int w = w0 + wl;
    const int* base = t + b * HW_ + w;
    int h0 = s * SH;

    unsigned tp[SH / 4];        // 4 regs: u8-packed targets for this segment
    int lastEq = -1, lastNeq = -1, firstEq = 256, firstNeq = 256;
    #pragma unroll
    for (int i = 0; i < SH; ++i) {
        int tv = base[(h0 + i) * W_];
        if ((i & 3) == 0) tp[i >> 2] = 0;
        tp[i >> 2] |= (unsigned)tv << ((i & 3) * 8);
        int h = h0 + i;
        if (tv == c) { lastEq = h;  if (firstEq  == 256) firstEq  = h; }
        else         { lastNeq = h; if (firstNeq == 256) firstNeq = h; }
    }
    __shared__ int sLE[SEG][32], sLN[SEG][32], sFE[SEG][32], sFN[SEG][32];
    sLE[s][wl] = lastEq; sLN[s][wl] = lastNeq;
    sFE[s][wl] = firstEq; sFN[s][wl] = firstNeq;
    __syncthreads();

    int carLE = -1, carLN = -1;
    for (int q = 0; q < s; ++q) {
        carLE = max(carLE, sLE[q][wl]);
        carLN = max(carLN, sLN[q][wl]);
    }
    int carFE = 256, carFN = 256;
    for (int q = s + 1; q < SEG; ++q) {
        carFE = min(carFE, sFE[q][wl]);
        carFN = min(carFN, sFN[q][wl]);
    }

    // tile has-fg: wave 0 lanes 0..31 each own a column
    bool pred = false;
    if (tid < 32) {
        int m = -1;
        #pragma unroll
        for (int q = 0; q < SEG; ++q) m = max(m, sLE[q][tid]);
        pred = (m >= 0);
    }
    bool anyfg = __any(pred);
    if (tid == 0) hasfg_p[blk] = anyfg ? 1 : 0;

    // forward pass: u8-encode dl-1 (255 = no zero at-or-above)
    unsigned ap[SH / 4];
    {
        int le = carLE, ln = carLN;
        #pragma unroll
        for (int i = 0; i < SH; ++i) {
            int h = h0 + i;
            int tv = (tp[i >> 2] >> ((i & 3) * 8)) & 0xFF;
            int lz;
            if (tv == c) { le = h; lz = ln; } else { ln = h; lz = le; }
            unsigned a = (lz < 0) ? 255u : (unsigned)(h - lz - 1);
            if ((i & 3) == 0) ap[i >> 2] = 0;
            ap[i >> 2] |= a << ((i & 3) * 8);
        }
    }
    // backward pass: d = min(dl, dn), u16 store
    {
        int fe = carFE, fn = carFN;
        unsigned short* gk = gpk + (size_t)bc * HW_ + w;
        #pragma unroll
        for (int i = SH - 1; i >= 0; --i) {
            int h = h0 + i;
            int tv = (tp[i >> 2] >> ((i & 3) * 8)) & 0xFF;
            int nz; bool fg;
            if (tv == c) { fe = h; fg = true;  nz = fn; }
            else         { fn = h; fg = false; nz = fe; }
            unsigned au = (ap[i >> 2] >> ((i & 3) * 8)) & 0xFF;
            int dl  = (au == 255u) ? 0x7FFF : (int)au + 1;
            int dnx = (nz > 255) ? 0x7FFF : (nz - h);
            int d = min(dl, dnx);
            gk[h * W_] = (unsigned short)(d | (fg ? 0x8000 : 0));
        }
    }
}

// ---------------------------------------------------------------------------
// K2 (fused): per-row horizontal EDT + raw dice sums. One wave per (bc,h)
// row; 8 rows (same bc) per 512-thr block (grid 3072, half the dispatches).
// PROLOGUE CHANGE vs R9/R10: hasfg + prob + gpk loads all issued
// unconditionally BEFORE the hf vote -> 3 independent ~900cy loads overlap
// instead of hasfg-vote-gpk serializing (saves ~900cy/wave).
// Scan: R9's per-radius-vote form (measured best). LDS 32.8KB -> 4 blk/CU
// = 32 waves/CU (occupancy cap).
// ---------------------------------------------------------------------------
__global__ void __launch_bounds__(512) k_edt(
                      const unsigned short* __restrict__ gpk,
                      const float* __restrict__ probs,
                      const int* __restrict__ hasfg_p,
                      float* __restrict__ part) {
    __shared__ float sp[8][LROW_];
    __shared__ float sn[8][LROW_];
    int wave = threadIdx.x >> 6;
    int lane = threadIdx.x & 63;
    int row = blockIdx.x * 8 + wave;       // bc*256 + h; all 8 rows same bc
    int bc = row >> 8;
    int h = row & (H_ - 1);

    // issue ALL independent global loads up front (overlapping latencies)
    int hfl = 0;
    if (lane < 8) hfl = hasfg_p[bc * 8 + lane];
    const float* prow = probs + (size_t)bc * HW_ + h * W_;
    float pv[4];
    #pragma unroll
    for (int i = 0; i < 4; ++i) pv[i] = prow[lane + 64 * i];
    const ushort4 v4 = ((const ushort4*)(gpk + (size_t)row * W_))[lane];

    bool hf = __any(hfl != 0);             // uniform across block (same bc)

    float dv[4];
    if (hf) {
        // pad init: left pad = float4 slots [0,32), right pad = slots [96,128)
        float4 inf4 = make_float4(3.0e38f, 3.0e38f, 3.0e38f, 3.0e38f);
        int slot = (lane < 32) ? lane : (lane + 64);
        ((float4*)&sp[wave][0])[slot] = inf4;
        ((float4*)&sn[wave][0])[slot] = inf4;

        float s1 = (float)(1000000 - h);
        float sent2 = s1 * s1;             // == fl((1e6 - h)^2), reference-exact
        float4 fpv, fnv;
        {
            const unsigned short* vs = (const unsigned short*)&v4;
            float* fp = (float*)&fpv;
            float* fn = (float*)&fnv;
            #pragma unroll
            for (int q = 0; q < 4; ++q) {
                unsigned v = vs[q];
                unsigned d = v & 0x7FFFu;
                float g2 = (d == 0x7FFFu) ? sent2 : (float)(d * d);
                bool fg = (v & 0x8000u) != 0;
                fp[q] = fg ? g2 : 0.0f;
                fn[q] = fg ? 0.0f : g2;
            }
        }
        ((float4*)&sp[wave][PADL_])[lane] = fpv;   // data at [128, 384)
        ((float4*)&sn[wave][PADL_])[lane] = fnv;
        // wave-private LDS rows: wave-local wait suffices (no barrier)
        asm volatile("s_waitcnt lgkmcnt(0)" ::: "memory");

        float bp[4], bn[4];
        #pragma unroll
        for (int i = 0; i < 4; ++i) {
            int j = PADL_ + lane + 64 * i;
            bp[i] = sp[wave][j];
            bn[i] = sn[wave][j];
        }
        // ---- neg transform scan ----
        {
            bool doneN = false;
            int r = 1;
            for (; r <= PADL_; ++r) {          // affine fast path (ds_read2)
                float fr = (float)r;
                float r2 = fr * fr;
                float m = fmaxf(fmaxf(bn[0], bn[1]), fmaxf(bn[2], bn[3]));
                if (!__any(r2 < m)) { doneN = true; break; }
                #pragma unroll
                for (int i = 0; i < 4; ++i) {
                    int j = PADL_ + lane + 64 * i;
                    float v = fminf(sn[wave][j - r], sn[wave][j + r]);
                    bn[i] = fminf(bn[i], fmaf(fr, fr, v));
                }
            }
            if (!doneN) {
                for (; r < W_; ++r) {          // rare tail: clamped reads
                    float fr = (float)r;
                    float r2 = fr * fr;
                    float m = fmaxf(fmaxf(bn[0], bn[1]), fmaxf(bn[2], bn[3]));
                    if (!__any(r2 < m)) break;
                    #pragma unroll
                    for (int i = 0; i < 4; ++i) {
                        int j = PADL_ + lane + 64 * i;
                        int jm = max(j - r, 0);
                        int jp = min(j + r, LROW_ - 1);
                        float v = fminf(sn[wave][jm], sn[wave][jp]);
                        bn[i] = fminf(bn[i], fmaf(fr, fr, v));
                    }
                }
            }
        }
        // ---- pos transform scan ----
        {
            bool doneP = false;
            int r = 1;
            for (; r <= PADL_; ++r) {          // affine fast path (ds_read2)
                float fr = (float)r;
                float r2 = fr * fr;
                float m = fmaxf(fmaxf(bp[0], bp[1]), fmaxf(bp[2], bp[3]));
                if (!__any(r2 < m)) { doneP = true; break; }
                #pragma unroll
                for (int i = 0; i < 4; ++i) {
                    int j = PADL_ + lane + 64 * i;
                    float v = fminf(sp[wave][j - r], sp[wave][j + r]);
                    bp[i] = fminf(bp[i], fmaf(fr, fr, v));
                }
            }
            if (!doneP) {
                for (; r < W_; ++r) {          // rare tail: clamped reads
                    float fr = (float)r;
                    float r2 = fr * fr;
                    float m = fmaxf(fmaxf(bp[0], bp[1]), fmaxf(bp[2], bp[3]));
                    if (!__any(r2 < m)) break;
                    #pragma unroll
                    for (int i = 0; i < 4; ++i) {
                        int j = PADL_ + lane + 64 * i;
                        int jm = max(j - r, 0);
                        int jp = min(j + r, LROW_ - 1);
                        float v = fminf(sp[wave][jm], sp[wave][jp]);
                        bp[i] = fminf(bp[i], fmaf(fr, fr, v));
                    }
                }
            }
        }
        #pragma unroll
        for (int i = 0; i < 4; ++i) dv[i] = sqrtf(bn[i]) - sqrtf(bp[i]);
    } else {
        #pragma unroll
        for (int i = 0; i < 4; ++i) dv[i] = 0.0f;
    }

    // raw sums over 256 pixels (pr from probs; order identical to before)
    float s_pd = 0.f, s_p = 0.f, s_pp = 0.f, s_d = 0.f, s_dd = 0.f;
    float mn = 3.4e38f, mx = -3.4e38f;
    #pragma unroll
    for (int i = 0; i < 4; ++i) {
        float pr = pv[i];
        float d = dv[i];
        s_pd = fmaf(pr, d, s_pd);
        s_p += pr;
        s_pp = fmaf(pr, pr, s_pp);
        s_d += d;
        s_dd = fmaf(d, d, s_dd);
        mn = fminf(mn, d);
        mx = fmaxf(mx, d);
    }
    #pragma unroll
    for (int off = 32; off; off >>= 1) {
        s_pd += __shfl_down(s_pd, off);
        s_p  += __shfl_down(s_p, off);
        s_pp += __shfl_down(s_pp, off);
        s_d  += __shfl_down(s_d, off);
        s_dd += __shfl_down(s_dd, off);
        mn = fminf(mn, __shfl_down(mn, off));
        mx = fmaxf(mx, __shfl_down(mx, off));
    }
    if (lane == 0) {
        float4* p4 = (float4*)(part + (size_t)row * 8);   // 32B-aligned
        p4[0] = make_float4(s_pd, s_p, s_pp, s_d);
        p4[1] = make_float4(s_dd, mn, mx, 0.0f);
    }
}

// ---------------------------------------------------------------------------
// K3: per-(b,c) reduce of 256 row partials -> dice -> atomicAdd loss term.
// out[0] zeroed by k_vs block 0. inter = sc*(S_pd - mn*S_p);
// d2 = sc^2*(S_dd - 2 mn S_d + mn^2 N). 96 atomics total.
// ---------------------------------------------------------------------------
__global__ void __launch_bounds__(256) k_bcred(
                       const float* __restrict__ part, float* __restrict__ out) {
    int bc = blockIdx.x;
    int tid = threadIdx.x;                 // 256
    const float4* p4 = (const float4*)(part + ((size_t)bc * 256 + tid) * 8);
    float4 a = p4[0], bq = p4[1];
    float s_pd = a.x, s_p = a.y, s_pp = a.z;
    float s_d = a.w, s_dd = bq.x, mn = bq.y, mx = bq.z;
    #pragma unroll
    for (int off = 32; off; off >>= 1) {
        s_pd += __shfl_down(s_pd, off);
        s_p  += __shfl_down(s_p, off);
        s_pp += __shfl_down(s_pp, off);
        s_d  += __shfl_down(s_d, off);
        s_dd += __shfl_down(s_dd, off);
        mn = fminf(mn, __shfl_down(mn, off));
        mx = fmaxf(mx, __shfl_down(mx, off));
    }
    __shared__ float red[4][7];
    int wave = tid >> 6, lane = tid & 63;
    if (lane == 0) {
        red[wave][0] = s_pd; red[wave][1] = s_p; red[wave][2] = s_pp;
        red[wave][3] = s_d;  red[wave][4] = s_dd; red[wave][5] = mn; red[wave][6] = mx;
    }
    __syncthreads();
    if (tid == 0) {
        s_pd = red[0][0]; s_p = red[0][1]; s_pp = red[0][2];
        s_d = red[0][3]; s_dd = red[0][4]; mn = red[0][5]; mx = red[0][6];
        for (int w = 1; w < 4; ++w) {
            s_pd += red[w][0]; s_p += red[w][1]; s_pp += red[w][2];
            s_d += red[w][3]; s_dd += red[w][4];
            mn = fminf(mn, red[w][5]); mx = fmaxf(mx, red[w][6]);
        }
        float sc = 1.0f / (mx - mn + 1e-8f);
        float inter = sc * (s_pd - mn * s_p);
        float d2 = sc * sc * (s_dd - 2.0f * mn * s_d + mn * mn * (float)HW_);
        float dice = 2.0f * inter / (s_pp + d2 + 1e-6f);
        atomicAdd(out, (1.0f - dice) * (1.0f / (float)NBC_));
    }
}

// ---------------------------------------------------------------------------
extern "C" void kernel_launch(void* const* d_in, const int* in_sizes, int n_in,
                              void* d_out, int out_size, void* d_ws, size_t ws_size,
                              hipStream_t stream) {
    const float* logits  = (const float*)d_in[0];
    const int*   targets = (const int*)d_in[1];
    float* out = (float*)d_out;

    // ws layout: gpk u16[96*65536] | hasfg_p i32[768] | part f32[24576*8] |
    //            probs f32[8*12*65536]
    unsigned short* gpk = (unsigned short*)d_ws;
    int* hasfg_p = (int*)(gpk + (size_t)NBC_ * HW_);
    float* part = (float*)(hasfg_p + NBC_ * 8);
    float* probs = part + (size_t)NBC_ * H_ * 8;

    k_vs<<<VB_ + SMB_, 512, 0, stream>>>(targets, logits, gpk,
                                         hasfg_p, probs, out);
    k_edt<<<NBC_ * H_ / 8, 512, 0, stream>>>(gpk, probs, hasfg_p, part);
    k_bcred<<<NBC_, 256, 0, stream>>>(part, out);
}